// Round 7
// baseline (84.078 us; speedup 1.0000x reference)
//
#include <hip/hip_runtime.h>
#include <hip/hip_bf16.h>

// B=8, Lq=2048, Lk=2048, D=256. out = softmax(mask? sq_i+sk_j : -1e9) @ V.
// sq cancels in softmax => out[i] = (mask[i]·(e*V)) / (mask[i]·e), e=exp(K·w).
// Stage 1: eb (bf16) + evB (pre-fragmented MFMA B-operand, coalesced loads).
// Stage 2: SPLIT-K partial GEMM (S=2): numerator and denominator are linear in
//   k, so each block does a 1024-k range; partials merge via atomicAdd (2
//   commutative f32 adds per cell -> deterministic). BM=64, BK=64, 512 thr
//   (8 waves 2m x 4n) -> grid 512, 16 waves/CU (2x round-6 occupancy).
//   Round-5 pipeline: A mask 2-step reg prefetch -> 3-deep LDS ring; B in-step
//   pre-fragged loads; per-step sync = lgkmcnt(0)+s_barrier (vmcnt never
//   drained). Denominator folded into MFMA via e-column B-frag (wn==0 waves).
// Stage 3: divide kernel out[row][:] /= denom[row].
// Workspace: evB 8 MB + eb 32 KB + denom 64 KB.

#define NB 8
#define LQ 2048
#define LK 2048
#define DD 256

typedef __attribute__((ext_vector_type(8))) short short8v;
typedef __attribute__((ext_vector_type(8))) unsigned short ushort8v;
typedef __attribute__((ext_vector_type(4))) float f32x4;

__device__ inline unsigned short f2bf(float x) {
  union { __hip_bfloat16 h; unsigned short u; } cv;
  cv.h = __float2bfloat16(x);
  return cv.u;
}

__device__ inline uint4 pack_mask8(const int4 a, const int4 b) {
  uint4 p;
  p.x = (a.x ? 0x3F80u : 0u) | (a.y ? 0x3F800000u : 0u);
  p.y = (a.z ? 0x3F80u : 0u) | (a.w ? 0x3F800000u : 0u);
  p.z = (b.x ? 0x3F80u : 0u) | (b.y ? 0x3F800000u : 0u);
  p.w = (b.z ? 0x3F80u : 0u) | (b.w ? 0x3F800000u : 0u);
  return p;
}

// ---------------- Stage 1: eb = bf16(exp(K·w)); evB = pre-fragmented e*V ------
// grid 8*64=512 (b = blk&7 -> XCD), 256 thr. Block owns batch b, 32 j-rows (ks).
__global__ __launch_bounds__(256) void bah_precompute(
    const float* __restrict__ key, const float* __restrict__ value,
    const float* __restrict__ w, unsigned short* __restrict__ evB,
    unsigned short* __restrict__ eb)
{
  __shared__ float e_s[32];
  __shared__ unsigned short t_s[32][260];   // padded: conflict-free transpose

  const int t = threadIdx.x;
  const int lane = t & 63;
  const int wid = t >> 6;                   // 0..3
  const int blk = blockIdx.x;
  const int b = blk & 7;
  const int ks = blk >> 3;                  // 0..63 (32-k slice)
  const int j0 = ks * 32;

  const float4 wv4 = reinterpret_cast<const float4*>(w)[lane];

  // e = exp(K·w): wave wid handles rows 8*wid..8*wid+7
#pragma unroll
  for (int r8 = 0; r8 < 8; ++r8) {
    const int r = wid * 8 + r8;
    const size_t row = (size_t)b * LK + j0 + r;
    const float4 kv = reinterpret_cast<const float4*>(key + row * DD)[lane];
    float s = kv.x * wv4.x + kv.y * wv4.y + kv.z * wv4.z + kv.w * wv4.w;
#pragma unroll
    for (int off = 32; off; off >>= 1) s += __shfl_xor(s, off);
    const float e = __expf(s);              // |K·w| small: no max-shift needed
    if (lane == 0) { e_s[r] = e; eb[row] = f2bf(e); }
  }
  __syncthreads();

  // e*V -> bf16 into padded LDS tile [j][d]
#pragma unroll
  for (int g = 0; g < 8; ++g) {
    const int jr = g * 4 + wid;
    const int d0 = lane * 4;
    const size_t row = (size_t)b * LK + j0 + jr;
    const float4 vv = reinterpret_cast<const float4*>(value + row * DD)[lane];
    const float e = e_s[jr];
    ushort4 u;
    u.x = f2bf(e * vv.x);
    u.y = f2bf(e * vv.y);
    u.z = f2bf(e * vv.z);
    u.w = f2bf(e * vv.w);
    *reinterpret_cast<ushort4*>(&t_s[jr][d0]) = u;
  }
  __syncthreads();

  // fragment gather + coalesced store: wave wid -> n-tiles 4*wid..4*wid+3.
  // Frag def (16x16x32 B-op): lane holds B[k=8*(lane>>4)+i][d=n*16+(lane&15)].
  const int lr = lane & 15;
  const int lj = lane >> 4;
#pragma unroll
  for (int n4 = 0; n4 < 4; ++n4) {
    const int n = wid * 4 + n4;
    ushort8v va;
#pragma unroll
    for (int i = 0; i < 8; ++i) va[i] = t_s[lj * 8 + i][n * 16 + lr];
    *reinterpret_cast<ushort8v*>(
        evB + ((size_t)((b * 64 + ks) * 16 + n) * 64 + lane) * 8) = va;
  }
}

// ---------------- Stage 2: split-K partial masked GEMM ------------------------
// grid 512: blk = b + 8*(itile + 32*s); b=blk&7 -> XCD (evB slice L2-resident).
// Block: 64 rows x 256 d x 1024 k. 512 thr = 8 waves (2m x 4n), wave 32x64.
__global__ __launch_bounds__(512, 4) void bah_gemm(
    const int* __restrict__ mask, const unsigned short* __restrict__ evB,
    const unsigned short* __restrict__ eb, float* __restrict__ out,
    float* __restrict__ denom)
{
  __shared__ unsigned short A_s[3][64 * 64];  // 3-deep ring of bf16 mask tiles

  const int t = threadIdx.x;
  const int lane = t & 63;
  const int wid = t >> 6;
  const int wm = wid >> 2;                  // 0..1: row half
  const int wn = wid & 3;                   // 0..3: d quarter
  const int lr = lane & 15;
  const int lj = lane >> 4;                 // k quarter / C row group

  const int blk = blockIdx.x;
  const int b = blk & 7;
  const int r = blk >> 3;
  const int i0 = (r & 31) * 64;
  const int s = r >> 5;                     // 0..1 k-split
  const int kb = s * 1024;                  // k base

  // A staging: thread -> row sr (8 thr/row), 8 ints at chunk c8
  const int sr = t >> 3;                    // 0..63
  const int c8 = t & 7;
  const int* aptr = mask + ((size_t)b * LQ + i0 + sr) * LK + kb + c8 * 8;
  const int awr = sr * 64 + ((c8 ^ (sr & 7)) * 8);   // swizzled ushort slot

  // B fragment pointers (pre-fragged evB): stride 8192 ushorts per 32-k slice
  const unsigned short* bB[4];
#pragma unroll
  for (int n = 0; n < 4; ++n)
    bB[n] = evB + ((size_t)(b * 64 + kb / 32) * 16 + wn * 4 + n) * 512 + lane * 8;
  const unsigned short* ebb = eb + b * LK + kb + lj * 8;

  // A frag read offsets: row = wm*32 + m*16 + lr; chunk (4h+lj) ^ (row&7)
  int afo[2][2];
#pragma unroll
  for (int m = 0; m < 2; ++m) {
    const int row = wm * 32 + m * 16 + lr;
#pragma unroll
    for (int h = 0; h < 2; ++h)
      afo[m][h] = row * 64 + (((4 * h + lj) ^ (row & 7)) * 8);
  }

  f32x4 acc[2][4] = {};
  f32x4 accd[2] = {};
  const short8v z8 = {};

  // ---- prologue: A(0) -> buf0; A(1) -> regs ----
  {
    const int4 p0 = *reinterpret_cast<const int4*>(aptr);
    const int4 p1 = *reinterpret_cast<const int4*>(aptr + 4);
    *reinterpret_cast<uint4*>(&A_s[0][awr]) = pack_mask8(p0, p1);
  }
  int4 aC0 = *reinterpret_cast<const int4*>(aptr + 64);
  int4 aC1 = *reinterpret_cast<const int4*>(aptr + 68);
  __syncthreads();

#pragma unroll 3
  for (int tt = 0; tt < 16; ++tt) {
    const int bufC = tt % 3;
    const int bufW = (tt + 1) % 3;

    // ---- issue A(t+2) + B(t)/e(t) loads (cross barrier via counted vmcnt) ----
    const int k2 = ((tt + 2) & 15) * 64;    // wrap: dead loads, harmless
    const int4 aN0 = *reinterpret_cast<const int4*>(aptr + k2);
    const int4 aN1 = *reinterpret_cast<const int4*>(aptr + k2 + 4);
    short8v bf0[4], bf1[4];
#pragma unroll
    for (int n = 0; n < 4; ++n) {
      bf0[n] = *reinterpret_cast<const short8v*>(bB[n] + (size_t)(2 * tt + 0) * 8192);
      bf1[n] = *reinterpret_cast<const short8v*>(bB[n] + (size_t)(2 * tt + 1) * 8192);
    }
    short8v ef0 = z8, ef1 = z8;
    if (wn == 0 && lr == 0) {
      ef0 = *reinterpret_cast<const short8v*>(ebb + tt * 64);
      ef1 = *reinterpret_cast<const short8v*>(ebb + tt * 64 + 32);
    }
    __builtin_amdgcn_sched_barrier(0);

    // ---- write A(t+1) (regs from last step), certify with lgkm+barrier only --
    *reinterpret_cast<uint4*>(&A_s[bufW][awr]) = pack_mask8(aC0, aC1);
    asm volatile("s_waitcnt lgkmcnt(0)" ::: "memory");
    __builtin_amdgcn_sched_barrier(0);
    __builtin_amdgcn_s_barrier();
    __builtin_amdgcn_sched_barrier(0);

    // ---- compute tile t ----
#pragma unroll
    for (int h = 0; h < 2; ++h) {
      const short8v a0 = *reinterpret_cast<const short8v*>(&A_s[bufC][afo[0][h]]);
      const short8v a1 = *reinterpret_cast<const short8v*>(&A_s[bufC][afo[1][h]]);
      if (wn == 0) {
        const short8v efh = h ? ef1 : ef0;
        accd[0] = __builtin_amdgcn_mfma_f32_16x16x32_bf16(a0, efh, accd[0], 0, 0, 0);
        accd[1] = __builtin_amdgcn_mfma_f32_16x16x32_bf16(a1, efh, accd[1], 0, 0, 0);
      }
#pragma unroll
      for (int n = 0; n < 4; ++n) {
        const short8v bv = h ? bf1[n] : bf0[n];
        acc[0][n] = __builtin_amdgcn_mfma_f32_16x16x32_bf16(a0, bv, acc[0][n], 0, 0, 0);
        acc[1][n] = __builtin_amdgcn_mfma_f32_16x16x32_bf16(a1, bv, acc[1][n], 0, 0, 0);
      }
    }
    aC0 = aN0; aC1 = aN1;
  }

  // ---- merge partials: atomicAdd (exactly 2 commutative adds per cell) ----
  if (wn == 0 && lr == 0) {
#pragma unroll
    for (int m = 0; m < 2; ++m)
#pragma unroll
      for (int rr = 0; rr < 4; ++rr)
        atomicAdd(denom + b * LQ + i0 + wm * 32 + m * 16 + lj * 4 + rr,
                  accd[m][rr]);
  }
#pragma unroll
  for (int m = 0; m < 2; ++m) {
    const int row0 = wm * 32 + m * 16 + lj * 4;
#pragma unroll
    for (int n = 0; n < 4; ++n) {
      const int col = wn * 64 + n * 16 + lr;
#pragma unroll
      for (int rr = 0; rr < 4; ++rr)
        atomicAdd(out + ((size_t)b * LQ + i0 + row0 + rr) * DD + col,
                  acc[m][n][rr]);
    }
  }
}

// ---------------- Stage 3: out[row][:] /= denom[row] --------------------------
__global__ __launch_bounds__(256) void bah_divide(
    float* __restrict__ out, const float* __restrict__ denom)
{
  const int t = threadIdx.x;
  const int row = blockIdx.x * 4 + (t >> 6);     // grid 4096 -> 16384 rows
  const int d4 = (t & 63) * 4;
  const float dn = denom[row];
  const float inv = (dn != 0.f) ? 1.f / dn : 0.f;  // all-masked: unreachable
  float4* p = reinterpret_cast<float4*>(out + (size_t)row * DD + d4);
  float4 v = *p;
  v.x *= inv; v.y *= inv; v.z *= inv; v.w *= inv;
  *p = v;
}

extern "C" void kernel_launch(void* const* d_in, const int* in_sizes, int n_in,
                              void* d_out, int out_size, void* d_ws, size_t ws_size,
                              hipStream_t stream) {
  // inputs: 0=query (unused: softmax shift-invariance), 1=key, 2=value, 3=mask, 4=w_align
  const float* key   = (const float*)d_in[1];
  const float* value = (const float*)d_in[2];
  const int*   mask  = (const int*)d_in[3];
  const float* w     = (const float*)d_in[4];
  float* out = (float*)d_out;

  unsigned short* evB = (unsigned short*)d_ws;                              // 8 MB
  unsigned short* eb  = (unsigned short*)((char*)d_ws + (size_t)NB * DD * LK * 2);
  float* denom = (float*)((char*)d_ws + (size_t)NB * DD * LK * 2 + NB * LK * 2);

  hipMemsetAsync(out, 0, (size_t)NB * LQ * DD * sizeof(float), stream);
  hipMemsetAsync(denom, 0, (size_t)NB * LQ * sizeof(float), stream);
  bah_precompute<<<NB * (LK / 32), 256, 0, stream>>>(key, value, w, evB, eb);
  bah_gemm<<<NB * (LQ / 64) * 2, 512, 0, stream>>>(mask, evB, eb, out, denom);
  bah_divide<<<NB * LQ / 4, 256, 0, stream>>>(out, denom);
}

// Round 8
// 68.899 us; speedup vs baseline: 1.2203x; 1.2203x over previous
//
#include <hip/hip_runtime.h>
#include <hip/hip_bf16.h>

// B=8, Lq=2048, Lk=2048, D=256. out = softmax(mask? sq_i+sk_j : -1e9) @ V.
// sq cancels in softmax => out[i] = (mask[i]·(e*V)) / (mask[i]·e), e=exp(K·w).
// Kernel 1 (fused prep):
//   blocks [0,512):   eb (bf16) + evB (pre-fragmented MFMA B-operand).
//   blocks [512,1536): BITPACK mask: 128 MB int32 -> 4 MB bits via __ballot
//                      (word w of row = bits k=32w..32w+31, LSB-first).
// Kernel 2 (GEMM): block = 64 rows x 128 d; whole A-tile's bits (16 KB) loaded
//   to LDS once -> K-loop has NO barriers, NO global A traffic: 4 ds_read_b32 +
//   ~50 VALU bit->bf16 expansion + 8 coalesced B-frag loads + 16 MFMA per step.
//   Denominator folded into MFMA via e-column B-frag (wn==0 waves).
// Workspace: evB 8 MB + eb 32 KB + pmask 4 MB.

#define NB 8
#define LQ 2048
#define LK 2048
#define DD 256

typedef __attribute__((ext_vector_type(8))) short short8v;
typedef __attribute__((ext_vector_type(8))) unsigned short ushort8v;
typedef __attribute__((ext_vector_type(4))) float f32x4;

__device__ inline unsigned short f2bf(float x) {
  union { __hip_bfloat16 h; unsigned short u; } cv;
  cv.h = __float2bfloat16(x);
  return cv.u;
}

// ---------------- Kernel 1: fused precompute + bitpack ------------------------
__global__ __launch_bounds__(256) void bah_prep(
    const float* __restrict__ key, const float* __restrict__ value,
    const float* __restrict__ w, const int* __restrict__ mask,
    unsigned short* __restrict__ evB, unsigned short* __restrict__ eb,
    unsigned int* __restrict__ pmask)
{
  __shared__ float e_s[32];
  __shared__ unsigned short t_s[32][260];   // padded: conflict-free transpose

  const int t = threadIdx.x;
  const int lane = t & 63;
  const int wid = t >> 6;                   // 0..3
  const int blk = blockIdx.x;

  if (blk < 512) {
    // ---- precompute: eb = bf16(exp(K·w)); evB = pre-fragmented e*V ----
    const int b = blk & 7;
    const int ks = blk >> 3;                // 0..63 (32-k slice)
    const int j0 = ks * 32;

    const float4 wv4 = reinterpret_cast<const float4*>(w)[lane];

#pragma unroll
    for (int r8 = 0; r8 < 8; ++r8) {
      const int r = wid * 8 + r8;
      const size_t row = (size_t)b * LK + j0 + r;
      const float4 kv = reinterpret_cast<const float4*>(key + row * DD)[lane];
      float s = kv.x * wv4.x + kv.y * wv4.y + kv.z * wv4.z + kv.w * wv4.w;
#pragma unroll
      for (int off = 32; off; off >>= 1) s += __shfl_xor(s, off);
      const float e = __expf(s);            // |K·w| small: no max-shift needed
      if (lane == 0) { e_s[r] = e; eb[row] = f2bf(e); }
    }
    __syncthreads();

#pragma unroll
    for (int g = 0; g < 8; ++g) {
      const int jr = g * 4 + wid;
      const size_t row = (size_t)b * LK + j0 + jr;
      const float4 vv = reinterpret_cast<const float4*>(value + row * DD)[lane];
      const float e = e_s[jr];
      ushort4 u;
      u.x = f2bf(e * vv.x);
      u.y = f2bf(e * vv.y);
      u.z = f2bf(e * vv.z);
      u.w = f2bf(e * vv.w);
      *reinterpret_cast<ushort4*>(&t_s[jr][lane * 4]) = u;
    }
    __syncthreads();

    // frag gather: lane holds B[k=8*(lane>>4)+i][d=n*16+(lane&15)]
    const int lr = lane & 15;
    const int lj = lane >> 4;
#pragma unroll
    for (int n4 = 0; n4 < 4; ++n4) {
      const int n = wid * 4 + n4;
      ushort8v va;
#pragma unroll
      for (int i = 0; i < 8; ++i) va[i] = t_s[lj * 8 + i][n * 16 + lr];
      *reinterpret_cast<ushort8v*>(
          evB + ((size_t)((b * 64 + ks) * 16 + n) * 64 + lane) * 8) = va;
    }
  } else {
    // ---- bitpack: 4 rows per wave, streaming ----
    const int gw = (blk - 512) * 4 + wid;   // 0..4095
#pragma unroll 1
    for (int r4 = 0; r4 < 4; ++r4) {
      const int rr = gw * 4 + r4;           // global row 0..16383
      const int* mrow = mask + (size_t)rr * LK;
      unsigned int myw = 0;
#pragma unroll
      for (int c = 0; c < 32; ++c) {
        const unsigned long long bal = __ballot(mrow[c * 64 + lane] != 0);
        const unsigned int sel = (lane & 1) ? (unsigned int)(bal >> 32)
                                            : (unsigned int)bal;
        myw = ((lane >> 1) == c) ? sel : myw;   // lane l keeps word l
      }
      pmask[(size_t)rr * 64 + lane] = myw;
    }
  }
}

// ---------------- Kernel 2: barrier-free masked GEMM --------------------------
// grid 512: b=blk&7 (XCD), i0=((blk>>3)&31)*64, dh=blk>>8 (d half).
// 256 thr = 4 waves (wm = wid>>1, wn = wid&1); wave tile 32 rows x 64 d.
__global__ __launch_bounds__(256, 2) void bah_gemm(
    const unsigned int* __restrict__ pmask, const unsigned short* __restrict__ evB,
    const unsigned short* __restrict__ eb, float* __restrict__ out)
{
  __shared__ unsigned int pb_s[64 * 66];    // padded: conflict-free b32 reads
  __shared__ float denom_s[64];

  const int t = threadIdx.x;
  const int lane = t & 63;
  const int wm = (t >> 7) & 1;
  const int wn = (t >> 6) & 1;
  const int lr = lane & 15;
  const int lj = lane >> 4;                 // 0..3

  const int blk = blockIdx.x;
  const int b = blk & 7;
  const int i0 = ((blk >> 3) & 31) * 64;
  const int dh = blk >> 8;                  // 0..1: d half

  // ---- load whole A-tile bits to LDS once (16 KB, coalesced) ----
  {
    const unsigned int* src =
        pmask + ((size_t)(b * LQ + i0 + (t >> 2))) * 64 + (t & 3) * 16;
    unsigned int* dst = &pb_s[(t >> 2) * 66 + (t & 3) * 16];
#pragma unroll
    for (int q = 0; q < 4; ++q)
      *reinterpret_cast<uint4*>(dst + q * 4) =
          *reinterpret_cast<const uint4*>(src + q * 4);
  }

  // B fragment pointers (pre-fragged evB): ntile = dh*8 + wn*4 + nn
  const unsigned short* bB[4];
#pragma unroll
  for (int nn = 0; nn < 4; ++nn)
    bB[nn] = evB + ((size_t)(b * 64) * 16 + dh * 8 + wn * 4 + nn) * 512 + lane * 8;
  const unsigned short* ebb = eb + b * LK + lj * 8;

  f32x4 acc[2][4] = {};
  f32x4 accd[2] = {};
  const short8v z8 = {};

  __syncthreads();   // pb_s ready; no barriers after this until epilogue

#pragma unroll 2
  for (int tt = 0; tt < 32; ++tt) {
#pragma unroll
    for (int h = 0; h < 2; ++h) {
      // ---- expand A frags from bits (LDS + VALU only) ----
      short8v af[2];
#pragma unroll
      for (int m = 0; m < 2; ++m) {
        const int row = wm * 32 + m * 16 + lr;
        const unsigned int word = pb_s[row * 66 + 2 * tt + h];
        const unsigned int byte = (word >> (8 * lj)) & 0xFFu;
        union { uint4 u; short8v s; } ex;
        ex.u.x = ((byte & 1u)   ? 0x3F80u : 0u) | ((byte & 2u)   ? 0x3F800000u : 0u);
        ex.u.y = ((byte & 4u)   ? 0x3F80u : 0u) | ((byte & 8u)   ? 0x3F800000u : 0u);
        ex.u.z = ((byte & 16u)  ? 0x3F80u : 0u) | ((byte & 32u)  ? 0x3F800000u : 0u);
        ex.u.w = ((byte & 64u)  ? 0x3F80u : 0u) | ((byte & 128u) ? 0x3F800000u : 0u);
        af[m] = ex.s;
      }
      // ---- B frags: coalesced 1KB loads from L2-resident evB ----
      short8v bf[4];
#pragma unroll
      for (int nn = 0; nn < 4; ++nn)
        bf[nn] = *reinterpret_cast<const short8v*>(
            bB[nn] + (size_t)(2 * tt + h) * 8192);
      // ---- denominator: e-column B-frag on wn==0 waves ----
      if (wn == 0) {
        short8v ef = z8;
        if (lr == 0)
          ef = *reinterpret_cast<const short8v*>(ebb + tt * 64 + h * 32);
        accd[0] = __builtin_amdgcn_mfma_f32_16x16x32_bf16(af[0], ef, accd[0], 0, 0, 0);
        accd[1] = __builtin_amdgcn_mfma_f32_16x16x32_bf16(af[1], ef, accd[1], 0, 0, 0);
      }
#pragma unroll
      for (int m = 0; m < 2; ++m)
#pragma unroll
        for (int nn = 0; nn < 4; ++nn)
          acc[m][nn] = __builtin_amdgcn_mfma_f32_16x16x32_bf16(
              af[m], bf[nn], acc[m][nn], 0, 0, 0);
    }
  }

  // ---- denominator broadcast (C col 0 lives in lanes with lr==0) ----
  if (wn == 0 && lr == 0) {
#pragma unroll
    for (int m = 0; m < 2; ++m)
#pragma unroll
      for (int r = 0; r < 4; ++r)
        denom_s[wm * 32 + m * 16 + lj * 4 + r] = accd[m][r];
  }
  __syncthreads();

  // ---- epilogue: divide and store (C layout: col=lane&15, row=lj*4+r) ----
#pragma unroll
  for (int m = 0; m < 2; ++m) {
    const int row0 = wm * 32 + m * 16 + lj * 4;
    float inv[4];
#pragma unroll
    for (int r = 0; r < 4; ++r) {
      const float dn = denom_s[row0 + r];
      inv[r] = (dn != 0.f) ? 1.f / dn : 0.f;   // all-masked row: avoid NaN
    }
#pragma unroll
    for (int nn = 0; nn < 4; ++nn) {
      const int col = dh * 128 + wn * 64 + nn * 16 + lr;
#pragma unroll
      for (int r = 0; r < 4; ++r)
        out[((size_t)b * LQ + (i0 + row0 + r)) * DD + col] = acc[m][nn][r] * inv[r];
    }
  }
}

extern "C" void kernel_launch(void* const* d_in, const int* in_sizes, int n_in,
                              void* d_out, int out_size, void* d_ws, size_t ws_size,
                              hipStream_t stream) {
  // inputs: 0=query (unused: softmax shift-invariance), 1=key, 2=value, 3=mask, 4=w_align
  const float* key   = (const float*)d_in[1];
  const float* value = (const float*)d_in[2];
  const int*   mask  = (const int*)d_in[3];
  const float* w     = (const float*)d_in[4];
  float* out = (float*)d_out;

  unsigned short* evB = (unsigned short*)d_ws;                              // 8 MB
  unsigned short* eb  = (unsigned short*)((char*)d_ws + (size_t)NB * DD * LK * 2);
  unsigned int* pmask = (unsigned int*)((char*)d_ws + (size_t)NB * DD * LK * 2
                                        + (size_t)NB * LK * 2);             // 4 MB

  bah_prep<<<1536, 256, 0, stream>>>(key, value, w, mask, evB, eb, pmask);
  bah_gemm<<<512, 256, 0, stream>>>(pmask, evB, eb, out);
}

// Round 9
// 52.601 us; speedup vs baseline: 1.5984x; 1.3098x over previous
//
#include <hip/hip_runtime.h>
#include <hip/hip_bf16.h>

// B=8, Lq=2048, Lk=2048, D=256. out = softmax(mask? sq_i+sk_j : -1e9) @ V.
// sq cancels in softmax => out[i] = (mask[i]·(e*V)) / (mask[i]·e), e=exp(K·w).
// Kernel 1: eb (bf16) + evB (pre-fragmented MFMA B-operand; coalesced loads).
// Kernel 2: mask-streaming GEMM. BM=128 x BN=128 x BK=64, 512 thr (8 waves,
//   2m x 4n, wave 64r x 32d) -> per-CU-step pipe costs all below the HBM mask
//   feed => kernel runs at the compulsory mask-stream rate. A: 3-deep LDS ring,
//   2-step register prefetch, XOR-swizzled (proven 0-conflict). B/e: register
//   prefetch ONE FULL STEP ahead. Sync: lgkmcnt(0)+s_barrier per step only —
//   vmcnt never drained. Denominator folded into MFMA (e-column B-frag, wn==0).
// Workspace: evB 8 MB + eb 32 KB.

#define NB 8
#define LQ 2048
#define LK 2048
#define DD 256

typedef __attribute__((ext_vector_type(8))) short short8v;
typedef __attribute__((ext_vector_type(8))) unsigned short ushort8v;
typedef __attribute__((ext_vector_type(4))) float f32x4;

__device__ inline unsigned short f2bf(float x) {
  union { __hip_bfloat16 h; unsigned short u; } cv;
  cv.h = __float2bfloat16(x);
  return cv.u;
}

__device__ inline uint4 pack_mask8(const int4 a, const int4 b) {
  uint4 p;
  p.x = (a.x ? 0x3F80u : 0u) | (a.y ? 0x3F800000u : 0u);
  p.y = (a.z ? 0x3F80u : 0u) | (a.w ? 0x3F800000u : 0u);
  p.z = (b.x ? 0x3F80u : 0u) | (b.y ? 0x3F800000u : 0u);
  p.w = (b.z ? 0x3F80u : 0u) | (b.w ? 0x3F800000u : 0u);
  return p;
}

// ---------------- Kernel 1: eb = bf16(exp(K·w)); evB = pre-fragmented e*V -----
// grid 8*64=512 (b = blk&7 -> XCD), 256 thr. Block owns batch b, 32 j-rows (ks).
__global__ __launch_bounds__(256) void bah_precompute(
    const float* __restrict__ key, const float* __restrict__ value,
    const float* __restrict__ w, unsigned short* __restrict__ evB,
    unsigned short* __restrict__ eb)
{
  __shared__ float e_s[32];
  __shared__ unsigned short t_s[32][260];   // padded: conflict-free transpose

  const int t = threadIdx.x;
  const int lane = t & 63;
  const int wid = t >> 6;                   // 0..3
  const int blk = blockIdx.x;
  const int b = blk & 7;
  const int ks = blk >> 3;                  // 0..63 (32-k slice)
  const int j0 = ks * 32;

  const float4 wv4 = reinterpret_cast<const float4*>(w)[lane];

#pragma unroll
  for (int r8 = 0; r8 < 8; ++r8) {
    const int r = wid * 8 + r8;
    const size_t row = (size_t)b * LK + j0 + r;
    const float4 kv = reinterpret_cast<const float4*>(key + row * DD)[lane];
    float s = kv.x * wv4.x + kv.y * wv4.y + kv.z * wv4.z + kv.w * wv4.w;
#pragma unroll
    for (int off = 32; off; off >>= 1) s += __shfl_xor(s, off);
    const float e = __expf(s);              // |K·w| small: no max-shift needed
    if (lane == 0) { e_s[r] = e; eb[row] = f2bf(e); }
  }
  __syncthreads();

#pragma unroll
  for (int g = 0; g < 8; ++g) {
    const int jr = g * 4 + wid;
    const size_t row = (size_t)b * LK + j0 + jr;
    const float4 vv = reinterpret_cast<const float4*>(value + row * DD)[lane];
    const float e = e_s[jr];
    ushort4 u;
    u.x = f2bf(e * vv.x);
    u.y = f2bf(e * vv.y);
    u.z = f2bf(e * vv.z);
    u.w = f2bf(e * vv.w);
    *reinterpret_cast<ushort4*>(&t_s[jr][lane * 4]) = u;
  }
  __syncthreads();

  // frag gather: lane holds B[k=8*(lane>>4)+i][d=n*16+(lane&15)]
  const int lr = lane & 15;
  const int lj = lane >> 4;
#pragma unroll
  for (int n4 = 0; n4 < 4; ++n4) {
    const int n = wid * 4 + n4;
    ushort8v va;
#pragma unroll
    for (int i = 0; i < 8; ++i) va[i] = t_s[lj * 8 + i][n * 16 + lr];
    *reinterpret_cast<ushort8v*>(
        evB + ((size_t)((b * 64 + ks) * 16 + n) * 64 + lane) * 8) = va;
  }
}

// ---------------- Kernel 2: mask-streaming masked GEMM ------------------------
// grid 256: blk = b + 8*(itile + 16*dh); 1 block/CU. 512 thr = 8 waves (2m x 4n).
__global__ __launch_bounds__(512, 1) void bah_gemm(
    const int* __restrict__ mask, const unsigned short* __restrict__ evB,
    const unsigned short* __restrict__ eb, float* __restrict__ out)
{
  __shared__ unsigned short A_s[3][128 * 64];  // 3-deep ring, 48 KB, swizzled
  __shared__ float denom_s[128];

  const int t = threadIdx.x;
  const int lane = t & 63;
  const int wid = t >> 6;                   // 0..7
  const int wm = wid >> 2;                  // 0..1: 64-row half
  const int wn = wid & 3;                   // 0..3: 32-d quarter
  const int lr = lane & 15;
  const int lj = lane >> 4;

  const int blk = blockIdx.x;
  const int b = blk & 7;                    // batch -> XCD (evB L2-resident)
  const int rr = blk >> 3;
  const int i0 = (rr & 15) * 128;
  const int dh = rr >> 4;                   // 0..1: d half

  // A staging: thread -> row sr (4 thr/row), 16 ints at cq*16
  const int sr = t >> 2;                    // 0..127
  const int cq = t & 3;
  const int* aptr = mask + ((size_t)b * LQ + i0 + sr) * LK + cq * 16;
  const int aw0 = sr * 64 + (((2 * cq + 0) ^ (sr & 7)) * 8);
  const int aw1 = sr * 64 + (((2 * cq + 1) ^ (sr & 7)) * 8);

  // B frag pointers (pre-fragged evB): stride 8192 ushorts per 32-k slice
  const unsigned short* bB[2];
#pragma unroll
  for (int nn = 0; nn < 2; ++nn)
    bB[nn] = evB + ((size_t)(b * 64) * 16 + dh * 8 + wn * 2 + nn) * 512 + lane * 8;
  const unsigned short* ebb = eb + b * LK + lj * 8;

  // A frag read offsets: row = wm*64 + m*16 + lr; chunk (4h+lj) ^ (row&7)
  int afo[4][2];
#pragma unroll
  for (int m = 0; m < 4; ++m) {
    const int row = wm * 64 + m * 16 + lr;
#pragma unroll
    for (int h = 0; h < 2; ++h)
      afo[m][h] = row * 64 + (((4 * h + lj) ^ (row & 7)) * 8);
  }

  f32x4 acc[4][2] = {};
  f32x4 accd[4] = {};
  const short8v z8 = {};

  short8v bfr[2][2][2];                     // [buf][h][nn] — 1 step ahead
  short8v efr[2][2] = {{z8, z8}, {z8, z8}};

  // ---- prologue: A(0)->ring0; A(1)->regs; B(0)/e(0)->reg buf0 ----
  {
    const int4 p0 = *reinterpret_cast<const int4*>(aptr + 0);
    const int4 p1 = *reinterpret_cast<const int4*>(aptr + 4);
    const int4 p2 = *reinterpret_cast<const int4*>(aptr + 8);
    const int4 p3 = *reinterpret_cast<const int4*>(aptr + 12);
    *reinterpret_cast<uint4*>(&A_s[0][aw0]) = pack_mask8(p0, p1);
    *reinterpret_cast<uint4*>(&A_s[0][aw1]) = pack_mask8(p2, p3);
  }
  int4 aC0 = *reinterpret_cast<const int4*>(aptr + 64);
  int4 aC1 = *reinterpret_cast<const int4*>(aptr + 68);
  int4 aC2 = *reinterpret_cast<const int4*>(aptr + 72);
  int4 aC3 = *reinterpret_cast<const int4*>(aptr + 76);
#pragma unroll
  for (int h = 0; h < 2; ++h) {
#pragma unroll
    for (int nn = 0; nn < 2; ++nn)
      bfr[0][h][nn] = *reinterpret_cast<const short8v*>(bB[nn] + (size_t)h * 8192);
    if (wn == 0 && lr == 0)
      efr[0][h] = *reinterpret_cast<const short8v*>(ebb + h * 32);
  }
  __syncthreads();

#pragma unroll 2
  for (int tt = 0; tt < 32; ++tt) {
    const int cur = tt & 1;
    const int nxt = cur ^ 1;
    const int bufC = tt % 3;
    const int bufW = (tt + 1) % 3;

    // ---- issue: A(t+2), B(t+1), e(t+1) (cross barrier via counted vmcnt) ----
    const int k2 = ((tt + 2) & 31) * 64;    // wrap: dead loads, harmless
    const int4 aN0 = *reinterpret_cast<const int4*>(aptr + k2);
    const int4 aN1 = *reinterpret_cast<const int4*>(aptr + k2 + 4);
    const int4 aN2 = *reinterpret_cast<const int4*>(aptr + k2 + 8);
    const int4 aN3 = *reinterpret_cast<const int4*>(aptr + k2 + 12);
    const int kn = ((tt + 1) & 31) * 2;
#pragma unroll
    for (int h = 0; h < 2; ++h) {
#pragma unroll
      for (int nn = 0; nn < 2; ++nn)
        bfr[nxt][h][nn] = *reinterpret_cast<const short8v*>(
            bB[nn] + (size_t)(kn + h) * 8192);
      short8v ev = z8;
      if (wn == 0 && lr == 0)
        ev = *reinterpret_cast<const short8v*>(ebb + (kn + h) * 32);
      efr[nxt][h] = ev;
    }
    __builtin_amdgcn_sched_barrier(0);

    // ---- write A(t+1) from regs; certify with lgkm + barrier only ----
    *reinterpret_cast<uint4*>(&A_s[bufW][aw0]) = pack_mask8(aC0, aC1);
    *reinterpret_cast<uint4*>(&A_s[bufW][aw1]) = pack_mask8(aC2, aC3);
    asm volatile("s_waitcnt lgkmcnt(0)" ::: "memory");
    __builtin_amdgcn_sched_barrier(0);
    __builtin_amdgcn_s_barrier();
    __builtin_amdgcn_sched_barrier(0);

    // ---- compute tile t from LDS-A + reg-B ----
#pragma unroll
    for (int h = 0; h < 2; ++h) {
      short8v af[4];
#pragma unroll
      for (int m = 0; m < 4; ++m)
        af[m] = *reinterpret_cast<const short8v*>(&A_s[bufC][afo[m][h]]);
      __builtin_amdgcn_s_setprio(1);
      if (wn == 0) {
#pragma unroll
        for (int m = 0; m < 4; ++m)
          accd[m] = __builtin_amdgcn_mfma_f32_16x16x32_bf16(
              af[m], efr[cur][h], accd[m], 0, 0, 0);
      }
#pragma unroll
      for (int m = 0; m < 4; ++m)
#pragma unroll
        for (int nn = 0; nn < 2; ++nn)
          acc[m][nn] = __builtin_amdgcn_mfma_f32_16x16x32_bf16(
              af[m], bfr[cur][h][nn], acc[m][nn], 0, 0, 0);
      __builtin_amdgcn_s_setprio(0);
    }
    aC0 = aN0; aC1 = aN1; aC2 = aN2; aC3 = aN3;
  }

  // ---- denominator broadcast (C col 0 lives in lanes with lr==0) ----
  if (wn == 0 && lr == 0) {
#pragma unroll
    for (int m = 0; m < 4; ++m)
#pragma unroll
      for (int q = 0; q < 4; ++q)
        denom_s[wm * 64 + m * 16 + lj * 4 + q] = accd[m][q];
  }
  __syncthreads();

  // ---- epilogue: divide and store (C layout: col=lane&15, row=lj*4+q) ----
#pragma unroll
  for (int m = 0; m < 4; ++m) {
    const int row0 = wm * 64 + m * 16 + lj * 4;
    float inv[4];
#pragma unroll
    for (int q = 0; q < 4; ++q) {
      const float dn = denom_s[row0 + q];
      inv[q] = (dn != 0.f) ? 1.f / dn : 0.f;   // all-masked row: avoid NaN
    }
#pragma unroll
    for (int nn = 0; nn < 2; ++nn) {
      const int col = dh * 128 + wn * 32 + nn * 16 + lr;
#pragma unroll
      for (int q = 0; q < 4; ++q)
        out[((size_t)b * LQ + (i0 + row0 + q)) * DD + col] = acc[m][nn][q] * inv[q];
    }
  }
}

extern "C" void kernel_launch(void* const* d_in, const int* in_sizes, int n_in,
                              void* d_out, int out_size, void* d_ws, size_t ws_size,
                              hipStream_t stream) {
  // inputs: 0=query (unused: softmax shift-invariance), 1=key, 2=value, 3=mask, 4=w_align
  const float* key   = (const float*)d_in[1];
  const float* value = (const float*)d_in[2];
  const int*   mask  = (const int*)d_in[3];
  const float* w     = (const float*)d_in[4];
  float* out = (float*)d_out;

  unsigned short* evB = (unsigned short*)d_ws;                              // 8 MB
  unsigned short* eb  = (unsigned short*)((char*)d_ws + (size_t)NB * DD * LK * 2);

  bah_precompute<<<NB * (LK / 32), 256, 0, stream>>>(key, value, w, evB, eb);
  bah_gemm<<<256, 512, 0, stream>>>(mask, evB, eb, out);
}

// Round 10
// 50.632 us; speedup vs baseline: 1.6606x; 1.0389x over previous
//
#include <hip/hip_runtime.h>
#include <hip/hip_bf16.h>

// B=8, Lq=2048, Lk=2048, D=256. out = softmax(mask? sq_i+sk_j : -1e9) @ V.
// sq cancels in softmax => out[i] = (mask[i]·(e*V)) / (mask[i]·e), e=exp(K·w).
// Kernel 1: eb (bf16) + evB (pre-fragmented MFMA B-operand; coalesced loads).
// Kernel 2: mask-streaming GEMM, BM=128 x BN=128 x BK=64, 512 thr (8 waves,
//   2m x 4n). ROUND-10 FIX: A-staging loads are now CONTIGUOUS per 4 lanes
//   (each wave instr = 16 rows x 64 B full sectors, not 64 scattered 16-B
//   pieces — 4x fewer L1 transactions). LDS uses per-row rotation swizzle
//   slot=(chunk+row)&7: <=2-way on b64 writes, bank-balanced b128 frag reads.
//   A: 3-deep LDS ring, 2-step reg prefetch. B/e: reg prefetch 1 step ahead.
//   Sync: lgkmcnt(0)+s_barrier only — vmcnt never drained. Denominator folded
//   into MFMA (e-column B-frag, wn==0 waves).
// Workspace: evB 8 MB + eb 32 KB.

#define NB 8
#define LQ 2048
#define LK 2048
#define DD 256

typedef __attribute__((ext_vector_type(8))) short short8v;
typedef __attribute__((ext_vector_type(8))) unsigned short ushort8v;
typedef __attribute__((ext_vector_type(4))) float f32x4;

__device__ inline unsigned short f2bf(float x) {
  union { __hip_bfloat16 h; unsigned short u; } cv;
  cv.h = __float2bfloat16(x);
  return cv.u;
}

__device__ inline uint2 pack_mask4(const int4 a) {
  uint2 p;
  p.x = (a.x ? 0x3F80u : 0u) | (a.y ? 0x3F800000u : 0u);
  p.y = (a.z ? 0x3F80u : 0u) | (a.w ? 0x3F800000u : 0u);
  return p;
}

// ---------------- Kernel 1: eb = bf16(exp(K·w)); evB = pre-fragmented e*V -----
// grid 8*64=512 (b = blk&7 -> XCD), 256 thr. Block owns batch b, 32 j-rows (ks).
__global__ __launch_bounds__(256) void bah_precompute(
    const float* __restrict__ key, const float* __restrict__ value,
    const float* __restrict__ w, unsigned short* __restrict__ evB,
    unsigned short* __restrict__ eb)
{
  __shared__ float e_s[32];
  __shared__ unsigned short t_s[32][260];   // padded: conflict-free transpose

  const int t = threadIdx.x;
  const int lane = t & 63;
  const int wid = t >> 6;                   // 0..3
  const int blk = blockIdx.x;
  const int b = blk & 7;
  const int ks = blk >> 3;                  // 0..63 (32-k slice)
  const int j0 = ks * 32;

  const float4 wv4 = reinterpret_cast<const float4*>(w)[lane];

#pragma unroll
  for (int r8 = 0; r8 < 8; ++r8) {
    const int r = wid * 8 + r8;
    const size_t row = (size_t)b * LK + j0 + r;
    const float4 kv = reinterpret_cast<const float4*>(key + row * DD)[lane];
    float s = kv.x * wv4.x + kv.y * wv4.y + kv.z * wv4.z + kv.w * wv4.w;
#pragma unroll
    for (int off = 32; off; off >>= 1) s += __shfl_xor(s, off);
    const float e = __expf(s);              // |K·w| small: no max-shift needed
    if (lane == 0) { e_s[r] = e; eb[row] = f2bf(e); }
  }
  __syncthreads();

#pragma unroll
  for (int g = 0; g < 8; ++g) {
    const int jr = g * 4 + wid;
    const size_t row = (size_t)b * LK + j0 + jr;
    const float4 vv = reinterpret_cast<const float4*>(value + row * DD)[lane];
    const float e = e_s[jr];
    ushort4 u;
    u.x = f2bf(e * vv.x);
    u.y = f2bf(e * vv.y);
    u.z = f2bf(e * vv.z);
    u.w = f2bf(e * vv.w);
    *reinterpret_cast<ushort4*>(&t_s[jr][lane * 4]) = u;
  }
  __syncthreads();

  // frag gather: lane holds B[k=8*(lane>>4)+i][d=n*16+(lane&15)]
  const int lr = lane & 15;
  const int lj = lane >> 4;
#pragma unroll
  for (int n4 = 0; n4 < 4; ++n4) {
    const int n = wid * 4 + n4;
    ushort8v va;
#pragma unroll
    for (int i = 0; i < 8; ++i) va[i] = t_s[lj * 8 + i][n * 16 + lr];
    *reinterpret_cast<ushort8v*>(
        evB + ((size_t)((b * 64 + ks) * 16 + n) * 64 + lane) * 8) = va;
  }
}

// ---------------- Kernel 2: mask-streaming masked GEMM ------------------------
// grid 256: blk = b + 8*(itile + 16*dh); 1 block/CU. 512 thr = 8 waves (2m x 4n).
__global__ __launch_bounds__(512, 1) void bah_gemm(
    const int* __restrict__ mask, const unsigned short* __restrict__ evB,
    const unsigned short* __restrict__ eb, float* __restrict__ out)
{
  __shared__ unsigned short A_s[3][128 * 64];  // 3-deep ring, 48 KB, rot-swizzled
  __shared__ float denom_s[128];

  const int t = threadIdx.x;
  const int lane = t & 63;
  const int wid = t >> 6;                   // 0..7
  const int wm = wid >> 2;                  // 0..1: 64-row half
  const int wn = wid & 3;                   // 0..3: 32-d quarter
  const int lr = lane & 15;
  const int lj = lane >> 4;

  const int blk = blockIdx.x;
  const int b = blk & 7;                    // batch -> XCD (evB L2-resident)
  const int rr = blk >> 3;
  const int i0 = (rr & 15) * 128;
  const int dh = rr >> 4;                   // 0..1: d half

  // ---- A staging: COALESCED. thread -> row sr (4 thr/row); lanes 0-3 read
  //      contiguous 64 B of one row; 4 loads j at +64 B stride cover 256 B. ----
  const int sr = t >> 2;                    // 0..127
  const int q = t & 3;
  const int* aptr = mask + ((size_t)b * LQ + i0 + sr) * LK + q * 4;
  // LDS write slots (ushort idx): k-ints kk = q*4 + j*16 -> 16B chunk c2 =
  // (q>>1)+2j, 8B half (q&1). Rotation swizzle: slot = (c2 + sr) & 7.
  int awr[4];
#pragma unroll
  for (int j = 0; j < 4; ++j)
    awr[j] = sr * 64 + ((((q >> 1) + 2 * j + sr) & 7) * 8) + (q & 1) * 4;

  // B frag pointers (pre-fragged evB): stride 8192 ushorts per 32-k slice
  const unsigned short* bB[2];
#pragma unroll
  for (int nn = 0; nn < 2; ++nn)
    bB[nn] = evB + ((size_t)(b * 64) * 16 + dh * 8 + wn * 2 + nn) * 512 + lane * 8;
  const unsigned short* ebb = eb + b * LK + lj * 8;

  // A frag read offsets: row = wm*64 + m*16 + lr; chunk (h*4+lj) rotated by row
  int afo[4][2];
#pragma unroll
  for (int m = 0; m < 4; ++m) {
    const int row = wm * 64 + m * 16 + lr;
#pragma unroll
    for (int h = 0; h < 2; ++h)
      afo[m][h] = row * 64 + (((h * 4 + lj + row) & 7) * 8);
  }

  f32x4 acc[4][2] = {};
  f32x4 accd[4] = {};
  const short8v z8 = {};

  short8v bfr[2][2][2];                     // [buf][h][nn] — 1 step ahead
  short8v efr[2][2] = {{z8, z8}, {z8, z8}};

  // ---- prologue: A(0)->ring0; A(1)->regs; B(0)/e(0)->reg buf0 ----
#pragma unroll
  for (int j = 0; j < 4; ++j) {
    const int4 p = *reinterpret_cast<const int4*>(aptr + j * 16);
    *reinterpret_cast<uint2*>(&A_s[0][awr[j]]) = pack_mask4(p);
  }
  int4 aC0 = *reinterpret_cast<const int4*>(aptr + 64 + 0);
  int4 aC1 = *reinterpret_cast<const int4*>(aptr + 64 + 16);
  int4 aC2 = *reinterpret_cast<const int4*>(aptr + 64 + 32);
  int4 aC3 = *reinterpret_cast<const int4*>(aptr + 64 + 48);
#pragma unroll
  for (int h = 0; h < 2; ++h) {
#pragma unroll
    for (int nn = 0; nn < 2; ++nn)
      bfr[0][h][nn] = *reinterpret_cast<const short8v*>(bB[nn] + (size_t)h * 8192);
    if (wn == 0 && lr == 0)
      efr[0][h] = *reinterpret_cast<const short8v*>(ebb + h * 32);
  }
  __syncthreads();

#pragma unroll 2
  for (int tt = 0; tt < 32; ++tt) {
    const int cur = tt & 1;
    const int nxt = cur ^ 1;
    const int bufC = tt % 3;
    const int bufW = (tt + 1) % 3;

    // ---- issue: A(t+2), B(t+1), e(t+1) (cross barrier via counted vmcnt) ----
    const int k2 = ((tt + 2) & 31) * 64;    // wrap: dead loads, harmless
    const int4 aN0 = *reinterpret_cast<const int4*>(aptr + k2 + 0);
    const int4 aN1 = *reinterpret_cast<const int4*>(aptr + k2 + 16);
    const int4 aN2 = *reinterpret_cast<const int4*>(aptr + k2 + 32);
    const int4 aN3 = *reinterpret_cast<const int4*>(aptr + k2 + 48);
    const int kn = ((tt + 1) & 31) * 2;
#pragma unroll
    for (int h = 0; h < 2; ++h) {
#pragma unroll
      for (int nn = 0; nn < 2; ++nn)
        bfr[nxt][h][nn] = *reinterpret_cast<const short8v*>(
            bB[nn] + (size_t)(kn + h) * 8192);
      short8v ev = z8;
      if (wn == 0 && lr == 0)
        ev = *reinterpret_cast<const short8v*>(ebb + (kn + h) * 32);
      efr[nxt][h] = ev;
    }
    __builtin_amdgcn_sched_barrier(0);

    // ---- write A(t+1) from regs; certify with lgkm + barrier only ----
    *reinterpret_cast<uint2*>(&A_s[bufW][awr[0]]) = pack_mask4(aC0);
    *reinterpret_cast<uint2*>(&A_s[bufW][awr[1]]) = pack_mask4(aC1);
    *reinterpret_cast<uint2*>(&A_s[bufW][awr[2]]) = pack_mask4(aC2);
    *reinterpret_cast<uint2*>(&A_s[bufW][awr[3]]) = pack_mask4(aC3);
    asm volatile("s_waitcnt lgkmcnt(0)" ::: "memory");
    __builtin_amdgcn_sched_barrier(0);
    __builtin_amdgcn_s_barrier();
    __builtin_amdgcn_sched_barrier(0);

    // ---- compute tile t from LDS-A + reg-B ----
#pragma unroll
    for (int h = 0; h < 2; ++h) {
      short8v af[4];
#pragma unroll
      for (int m = 0; m < 4; ++m)
        af[m] = *reinterpret_cast<const short8v*>(&A_s[bufC][afo[m][h]]);
      __builtin_amdgcn_s_setprio(1);
      if (wn == 0) {
#pragma unroll
        for (int m = 0; m < 4; ++m)
          accd[m] = __builtin_amdgcn_mfma_f32_16x16x32_bf16(
              af[m], efr[cur][h], accd[m], 0, 0, 0);
      }
#pragma unroll
      for (int m = 0; m < 4; ++m)
#pragma unroll
        for (int nn = 0; nn < 2; ++nn)
          acc[m][nn] = __builtin_amdgcn_mfma_f32_16x16x32_bf16(
              af[m], bfr[cur][h][nn], acc[m][nn], 0, 0, 0);
      __builtin_amdgcn_s_setprio(0);
    }
    aC0 = aN0; aC1 = aN1; aC2 = aN2; aC3 = aN3;
  }

  // ---- denominator broadcast (C col 0 lives in lanes with lr==0) ----
  if (wn == 0 && lr == 0) {
#pragma unroll
    for (int m = 0; m < 4; ++m)
#pragma unroll
      for (int qq = 0; qq < 4; ++qq)
        denom_s[wm * 64 + m * 16 + lj * 4 + qq] = accd[m][qq];
  }
  __syncthreads();

  // ---- epilogue: divide and store (C layout: col=lane&15, row=lj*4+q) ----
#pragma unroll
  for (int m = 0; m < 4; ++m) {
    const int row0 = wm * 64 + m * 16 + lj * 4;
    float inv[4];
#pragma unroll
    for (int qq = 0; qq < 4; ++qq) {
      const float dn = denom_s[row0 + qq];
      inv[qq] = (dn != 0.f) ? 1.f / dn : 0.f;   // all-masked row: avoid NaN
    }
#pragma unroll
    for (int nn = 0; nn < 2; ++nn) {
      const int col = dh * 128 + wn * 32 + nn * 16 + lr;
#pragma unroll
      for (int qq = 0; qq < 4; ++qq)
        out[((size_t)b * LQ + (i0 + row0 + qq)) * DD + col] = acc[m][nn][qq] * inv[qq];
    }
  }
}

extern "C" void kernel_launch(void* const* d_in, const int* in_sizes, int n_in,
                              void* d_out, int out_size, void* d_ws, size_t ws_size,
                              hipStream_t stream) {
  // inputs: 0=query (unused: softmax shift-invariance), 1=key, 2=value, 3=mask, 4=w_align
  const float* key   = (const float*)d_in[1];
  const float* value = (const float*)d_in[2];
  const int*   mask  = (const int*)d_in[3];
  const float* w     = (const float*)d_in[4];
  float* out = (float*)d_out;

  unsigned short* evB = (unsigned short*)d_ws;                              // 8 MB
  unsigned short* eb  = (unsigned short*)((char*)d_ws + (size_t)NB * DD * LK * 2);

  bah_precompute<<<NB * (LK / 32), 256, 0, stream>>>(key, value, w, evB, eb);
  bah_gemm<<<256, 512, 0, stream>>>(mask, evB, eb, out);
}